// Round 5
// baseline (237.687 us; speedup 1.0000x reference)
//
#include <hip/hip_runtime.h>
#include <hip/hip_bf16.h>

#define NN 4096
#define FF 128
#define NC 80     // 64 value cols + 8 expEr cols + 1 ones col + 7 pad
#define HPAD 136  // H row stride in shorts (128 + 8): breaks LDS bank conflicts

typedef __attribute__((ext_vector_type(4))) float float4v;
typedef __attribute__((ext_vector_type(4))) unsigned int uint4v;
typedef __attribute__((ext_vector_type(8))) short short8;
typedef __attribute__((ext_vector_type(8))) unsigned short ushort8;
typedef __attribute__((ext_vector_type(4))) unsigned short ushort4v;

static __device__ inline unsigned short bfb(float x) {
    __hip_bfloat16 b = __float2bfloat16(x);
    return *(unsigned short*)&b;
}
static __device__ inline float bff(unsigned short u) {
    __hip_bfloat16 b = *(__hip_bfloat16*)&u;
    return __bfloat162float(b);
}

// ---------------------------------------------------------------------------
// Kernel 1 (MFMA prep): HW = H@W via split-bf16 (hi+lo residual, 3 cross-term
// MFMAs -> ~2^-17 rel err). B operand carries 16 extra pre-contracted columns
// wr[h,f] = sum_u W[h,f,u]*ar[h,u] (cols 64..71) and wl (cols 72..79), so
// e_r[h,j] / e_l[h,j] come straight out of accumulator n-tile 4.
// Writes Bp (bf16, MFMA B-fragment layout), expEl (f32), and zeroes the
// split-K completion counters used by the fused GEMM.
// ---------------------------------------------------------------------------
__global__ __launch_bounds__(128) void gat_prep(const float* __restrict__ H,
                                                const float* __restrict__ W,
                                                const float* __restrict__ al,
                                                const float* __restrict__ ar,
                                                float* __restrict__ expEl,
                                                __hip_bfloat16* __restrict__ Bp,
                                                int* __restrict__ counters)
{
    __shared__ unsigned short Hhi[32 * HPAD], Hlo[32 * HPAD];
    __shared__ unsigned short Whi[16 * NC * 8], Wlo[16 * NC * 8];
    const int t  = threadIdx.x;
    const int j0 = blockIdx.x * 32;

    if (blockIdx.x == 0 && t < 64) counters[t] = 0;

    // ---- stage H rows j0..j0+31 as hi/lo bf16 (row-major, HPAD stride) ----
    {
        const int jr = t >> 2, f0 = (t & 3) * 32;
        const float* src = H + (size_t)(j0 + jr) * FF + f0;
        unsigned short* dh = Hhi + jr * HPAD + f0;
        unsigned short* dl = Hlo + jr * HPAD + f0;
        #pragma unroll
        for (int i = 0; i < 32; i += 4) {
            float4v x = *(const float4v*)(src + i);
            ushort4v hv, lv;
            #pragma unroll
            for (int c2 = 0; c2 < 4; ++c2) {
                unsigned short h = bfb(x[c2]);
                hv[c2] = h;
                lv[c2] = bfb(x[c2] - bff(h));
            }
            *(ushort4v*)(dh + i) = hv;
            *(ushort4v*)(dl + i) = lv;
        }
    }
    // ---- stage W value-cols 0..63 in B-fragment layout (hi/lo) ----
    {
        const int hu = t & 63;
        const int fb = (t >> 6) * 64;   // wave 0: f 0..63, wave 1: f 64..127
        const float* wsrc = W + (size_t)(hu >> 3) * (FF * 8) + (hu & 7);
        #pragma unroll
        for (int g8 = 0; g8 < 8; ++g8) {
            const int f0 = fb + g8 * 8;
            ushort8 hv, lv;
            #pragma unroll
            for (int i = 0; i < 8; ++i) {
                float x = wsrc[(size_t)(f0 + i) * 8];
                unsigned short h = bfb(x);
                hv[i] = h; lv[i] = bfb(x - bff(h));
            }
            const int g = (f0 >> 5) * 4 + ((f0 >> 3) & 3);
            *(ushort8*)&Whi[((size_t)g * NC + hu) * 8] = hv;
            *(ushort8*)&Wlo[((size_t)g * NC + hu) * 8] = lv;
        }
    }
    // ---- build contracted cols: wr (64..71), wl (72..79) ----
    {
        const int h  = t >> 4;          // 0..7
        const int f0 = (t & 15) * 8;    // 0..120, 8-aligned
        float arv[8], alv[8];
        #pragma unroll
        for (int u = 0; u < 8; ++u) { arv[u] = ar[h * 8 + u]; alv[u] = al[h * 8 + u]; }
        ushort8 rh, rl, lh, ll;
        #pragma unroll
        for (int i = 0; i < 8; ++i) {
            const float* wp = W + (size_t)h * (FF * 8) + (size_t)(f0 + i) * 8;
            float sr = 0.f, sl = 0.f;
            #pragma unroll
            for (int u = 0; u < 8; ++u) { float w = wp[u]; sr += w * arv[u]; sl += w * alv[u]; }
            unsigned short a = bfb(sr); rh[i] = a; rl[i] = bfb(sr - bff(a));
            unsigned short b = bfb(sl); lh[i] = b; ll[i] = bfb(sl - bff(b));
        }
        const int g = (f0 >> 5) * 4 + ((f0 >> 3) & 3);
        *(ushort8*)&Whi[((size_t)g * NC + 64 + h) * 8] = rh;
        *(ushort8*)&Wlo[((size_t)g * NC + 64 + h) * 8] = rl;
        *(ushort8*)&Whi[((size_t)g * NC + 72 + h) * 8] = lh;
        *(ushort8*)&Wlo[((size_t)g * NC + 72 + h) * 8] = ll;
    }
    __syncthreads();

    // ---- MFMA: [32j x 128f] @ [128f x 80c], split-bf16 (3 cross terms) ----
    const int w = t >> 6, lane = t & 63;
    const int m16 = lane & 15, q = lane >> 4;

    float4v acc[5] = {};
    #pragma unroll
    for (int kt = 0; kt < 4; ++kt) {
        short8 ahi = *(const short8*)&Hhi[(w * 16 + m16) * HPAD + kt * 32 + q * 8];
        short8 alo = *(const short8*)&Hlo[(w * 16 + m16) * HPAD + kt * 32 + q * 8];
        #pragma unroll
        for (int nt = 0; nt < 5; ++nt) {
            short8 bhi = *(const short8*)&Whi[((size_t)(kt * 4 + q) * NC + nt * 16 + m16) * 8];
            short8 blo = *(const short8*)&Wlo[((size_t)(kt * 4 + q) * NC + nt * 16 + m16) * 8];
            acc[nt] = __builtin_amdgcn_mfma_f32_16x16x32_bf16(ahi, bhi, acc[nt], 0, 0, 0);
            acc[nt] = __builtin_amdgcn_mfma_f32_16x16x32_bf16(alo, bhi, acc[nt], 0, 0, 0);
            acc[nt] = __builtin_amdgcn_mfma_f32_16x16x32_bf16(ahi, blo, acc[nt], 0, 0, 0);
        }
    }

    // acc[4] col 64+m16: m16<8 -> e_r[h=m16]; m16>=8 -> e_l[h=m16-8]
    const int jbase = j0 + w * 16 + q * 4;
    float ex[4];
    #pragma unroll
    for (int r = 0; r < 4; ++r) ex[r] = expf(acc[4][r]);
    if (m16 >= 8) {
        #pragma unroll
        for (int r = 0; r < 4; ++r)
            expEl[(m16 - 8) * NN + jbase + r] = ex[r];
    }
    #pragma unroll
    for (int r = 0; r < 4; ++r) {
        const int j = jbase + r;
        const size_t base = ((size_t)((j >> 5) * 4 + ((j >> 3) & 3)) * NC) * 8 + (j & 7);
        #pragma unroll
        for (int nt = 0; nt < 4; ++nt) {
            // col c = nt*16+m16 -> h = 2nt + (m16>>3); expEr[h] lives on lane (q, m16'=h)
            const int srcl = (lane & 48) | (nt * 2 + (m16 >> 3));
            const float er = __shfl(ex[r], srcl);
            Bp[base + (size_t)(nt * 16 + m16) * 8] = __float2bfloat16(er * acc[nt][r]);
        }
        const float v = (m16 < 8) ? ex[r] : (m16 == 8 ? 1.0f : 0.0f);
        Bp[base + (size_t)(64 + m16) * 8] = __float2bfloat16(v);
    }
}

// ---------------------------------------------------------------------------
// Kernel 2 (fused): C[i,c] = sum_j A[i,j]*B[j,c]; M=4096, N=80, K=4096 split
// over KC chunks. A f32 0/1 truncated to bf16 in-register (exact).
// Split-K completion: last block per rb reduces partials (agent-scope loads —
// per-XCD L2s are NOT coherent and hold stale poison) and applies denom+elu.
// ---------------------------------------------------------------------------
__global__ __launch_bounds__(256) void gat_gemm(const float* __restrict__ A,
                                                const __hip_bfloat16* __restrict__ Bp,
                                                float* __restrict__ Cp,
                                                int* __restrict__ counters,
                                                const float* __restrict__ expEl,
                                                float* __restrict__ out,
                                                int ktiles, int KC)
{
    const int rb   = blockIdx.x;
    const int kc   = blockIdx.y;
    const int wave = threadIdx.x >> 6;
    const int lane = threadIdx.x & 63;
    const int m16  = lane & 15;
    const int q    = lane >> 4;
    const int row0 = rb * 64 + wave * 16;

    float4v acc[5] = {};

    const int k0 = kc * (ktiles * 32);
    const unsigned int* Au = (const unsigned int*)A;
    const short* Bs = (const short*)Bp;
    const unsigned int* arow = Au + (size_t)(row0 + m16) * NN + q * 8;

    uint4v a0 = *(const uint4v*)(arow + k0);
    uint4v a1 = *(const uint4v*)(arow + k0 + 4);

    for (int kt = 0; kt < ktiles; ++kt) {
        const int kk = k0 + kt * 32;
        short8 afrag;
        afrag[0] = (short)(a0[0] >> 16); afrag[1] = (short)(a0[1] >> 16);
        afrag[2] = (short)(a0[2] >> 16); afrag[3] = (short)(a0[3] >> 16);
        afrag[4] = (short)(a1[0] >> 16); afrag[5] = (short)(a1[1] >> 16);
        afrag[6] = (short)(a1[2] >> 16); afrag[7] = (short)(a1[3] >> 16);

        if (kt + 1 < ktiles) {            // prefetch next A tile
            a0 = *(const uint4v*)(arow + kk + 32);
            a1 = *(const uint4v*)(arow + kk + 36);
        }

        const int ktg = kk >> 5;
        const short8* bbase = (const short8*)(Bs + ((size_t)(ktg * 4 + q) * NC) * 8);
        #pragma unroll
        for (int nt = 0; nt < 5; ++nt) {
            short8 bfrag = bbase[nt * 16 + m16];
            acc[nt] = __builtin_amdgcn_mfma_f32_16x16x32_bf16(afrag, bfrag, acc[nt], 0, 0, 0);
        }
    }

    float* cbase = Cp + (size_t)kc * NN * NC;
    #pragma unroll
    for (int nt = 0; nt < 5; ++nt) {
        #pragma unroll
        for (int r = 0; r < 4; ++r) {
            const int row = row0 + q * 4 + r;   // C/D: col=lane&15, row=(lane>>4)*4+reg
            const int col = nt * 16 + m16;
            cbase[(size_t)row * NC + col] = acc[nt][r];
        }
    }

    // ---- split-K completion: last block for this rb reduces + epilogue ----
    __threadfence();          // make partials visible at agent scope
    __syncthreads();          // all threads' stores+fences precede the atomic
    __shared__ int sOld;
    if (threadIdx.x == 0)
        sOld = __hip_atomic_fetch_add(&counters[rb], 1, __ATOMIC_ACQ_REL,
                                      __HIP_MEMORY_SCOPE_AGENT);
    __syncthreads();
    if (sOld != KC - 1) return;
    __threadfence();          // acquire side

    for (int p = threadIdx.x; p < 64 * 64; p += 256) {
        const int i = rb * 64 + (p >> 6);
        const int c = p & 63;             // h*8+u
        const int h = c >> 3;
        float T = 0.f, S = 0.f, dg = 0.f;
        for (int k = 0; k < KC; ++k) {
            const float* row = Cp + ((size_t)k * NN + i) * NC;
            T  += __hip_atomic_load(&row[c],      __ATOMIC_RELAXED, __HIP_MEMORY_SCOPE_AGENT);
            S  += __hip_atomic_load(&row[64 + h], __ATOMIC_RELAXED, __HIP_MEMORY_SCOPE_AGENT);
            dg += __hip_atomic_load(&row[72],     __ATOMIC_RELAXED, __HIP_MEMORY_SCOPE_AGENT);
        }
        const float el = expEl[h * NN + i];
        const float denom = ((float)NN - dg) + el * S;
        const float x = el * T / denom;
        out[(size_t)i * 64 + c] = x > 0.f ? x : expf(x) - 1.f;
    }
}

extern "C" void kernel_launch(void* const* d_in, const int* in_sizes, int n_in,
                              void* d_out, int out_size, void* d_ws, size_t ws_size,
                              hipStream_t stream) {
    const float* A  = (const float*)d_in[0];
    const float* H  = (const float*)d_in[1];
    const float* W  = (const float*)d_in[2];
    const float* al = (const float*)d_in[3];
    const float* ar = (const float*)d_in[4];
    float* out = (float*)d_out;

    // workspace layout
    float* expEl = (float*)d_ws;                                   // 8*4096 f32 = 128 KB
    __hip_bfloat16* Bp = (__hip_bfloat16*)((char*)d_ws + 131072);  // 128*4*80*8 bf16 = 640 KB
    int* counters = (int*)((char*)d_ws + 131072 + 655360);         // 64 ints (pad to 1 KB)
    float* Cp = (float*)((char*)d_ws + 131072 + 655360 + 1024);    // KC*4096*80 f32

    const size_t fixed = 131072 + 655360 + 1024;
    int KC = 8;
    while (KC > 1 && fixed + (size_t)KC * NN * NC * 4 > ws_size) KC >>= 1;
    const int ktiles = NN / (KC * 32);

    gat_prep<<<NN / 32, 128, 0, stream>>>(H, W, al, ar, expEl, Bp, counters);
    gat_gemm<<<dim3(NN / 64, KC), 256, 0, stream>>>(A, Bp, Cp, counters, expEl, out, ktiles, KC);
}

// Round 6
// 115.786 us; speedup vs baseline: 2.0528x; 2.0528x over previous
//
#include <hip/hip_runtime.h>
#include <hip/hip_bf16.h>

#define NN 4096
#define FF 128
#define NC 80     // 64 value cols + 8 expEr cols + 1 ones col + 7 pad
#define HPAD 136  // H row stride in shorts (128 + 8): breaks LDS bank conflicts
#define LSTR 84   // LDS partial-tile row stride in floats (84%32=20 -> 2-way max)

typedef __attribute__((ext_vector_type(4))) float float4v;
typedef __attribute__((ext_vector_type(4))) unsigned int uint4v;
typedef __attribute__((ext_vector_type(8))) short short8;
typedef __attribute__((ext_vector_type(8))) unsigned short ushort8;
typedef __attribute__((ext_vector_type(4))) unsigned short ushort4v;

static __device__ inline unsigned short bfb(float x) {
    __hip_bfloat16 b = __float2bfloat16(x);
    return *(unsigned short*)&b;
}
static __device__ inline float bff(unsigned short u) {
    __hip_bfloat16 b = *(__hip_bfloat16*)&u;
    return __bfloat162float(b);
}

// ---------------------------------------------------------------------------
// Kernel 1 (MFMA prep): HW = H@W via split-bf16 (hi+lo residual, 3 cross-term
// MFMAs -> ~2^-17 rel err). B operand carries 16 extra pre-contracted columns
// wr[h,f] = sum_u W[h,f,u]*ar[h,u] (cols 64..71) and wl (cols 72..79), so
// e_r[h,j] / e_l[h,j] come straight out of accumulator n-tile 4.
// Writes Bp (bf16, MFMA B-fragment layout: elem (k=j,c) at
//   [((j>>5)*4+((j>>3)&3))*NC + c]*8 + (j&7)) and expEl[h*NN+j] (f32).
// ---------------------------------------------------------------------------
__global__ __launch_bounds__(128) void gat_prep(const float* __restrict__ H,
                                                const float* __restrict__ W,
                                                const float* __restrict__ al,
                                                const float* __restrict__ ar,
                                                float* __restrict__ expEl,
                                                __hip_bfloat16* __restrict__ Bp)
{
    __shared__ unsigned short Hhi[32 * HPAD], Hlo[32 * HPAD];
    __shared__ unsigned short Whi[16 * NC * 8], Wlo[16 * NC * 8];
    const int t  = threadIdx.x;
    const int j0 = blockIdx.x * 32;

    // ---- stage H rows j0..j0+31 as hi/lo bf16 (row-major, HPAD stride) ----
    {
        const int jr = t >> 2, f0 = (t & 3) * 32;
        const float* src = H + (size_t)(j0 + jr) * FF + f0;
        unsigned short* dh = Hhi + jr * HPAD + f0;
        unsigned short* dl = Hlo + jr * HPAD + f0;
        #pragma unroll
        for (int i = 0; i < 32; i += 4) {
            float4v x = *(const float4v*)(src + i);
            ushort4v hv, lv;
            #pragma unroll
            for (int c2 = 0; c2 < 4; ++c2) {
                unsigned short h = bfb(x[c2]);
                hv[c2] = h;
                lv[c2] = bfb(x[c2] - bff(h));
            }
            *(ushort4v*)(dh + i) = hv;
            *(ushort4v*)(dl + i) = lv;
        }
    }
    // ---- stage W value-cols 0..63 in B-fragment layout (hi/lo) ----
    {
        const int hu = t & 63;
        const int fb = (t >> 6) * 64;   // wave 0: f 0..63, wave 1: f 64..127
        const float* wsrc = W + (size_t)(hu >> 3) * (FF * 8) + (hu & 7);
        #pragma unroll
        for (int g8 = 0; g8 < 8; ++g8) {
            const int f0 = fb + g8 * 8;
            ushort8 hv, lv;
            #pragma unroll
            for (int i = 0; i < 8; ++i) {
                float x = wsrc[(size_t)(f0 + i) * 8];
                unsigned short h = bfb(x);
                hv[i] = h; lv[i] = bfb(x - bff(h));
            }
            const int g = (f0 >> 5) * 4 + ((f0 >> 3) & 3);
            *(ushort8*)&Whi[((size_t)g * NC + hu) * 8] = hv;
            *(ushort8*)&Wlo[((size_t)g * NC + hu) * 8] = lv;
        }
    }
    // ---- build contracted cols: wr (64..71), wl (72..79) ----
    {
        const int h  = t >> 4;          // 0..7
        const int f0 = (t & 15) * 8;    // 0..120, 8-aligned
        float arv[8], alv[8];
        #pragma unroll
        for (int u = 0; u < 8; ++u) { arv[u] = ar[h * 8 + u]; alv[u] = al[h * 8 + u]; }
        ushort8 rh, rl, lh, ll;
        #pragma unroll
        for (int i = 0; i < 8; ++i) {
            const float* wp = W + (size_t)h * (FF * 8) + (size_t)(f0 + i) * 8;
            float sr = 0.f, sl = 0.f;
            #pragma unroll
            for (int u = 0; u < 8; ++u) { float w = wp[u]; sr += w * arv[u]; sl += w * alv[u]; }
            unsigned short a = bfb(sr); rh[i] = a; rl[i] = bfb(sr - bff(a));
            unsigned short b = bfb(sl); lh[i] = b; ll[i] = bfb(sl - bff(b));
        }
        const int g = (f0 >> 5) * 4 + ((f0 >> 3) & 3);
        *(ushort8*)&Whi[((size_t)g * NC + 64 + h) * 8] = rh;
        *(ushort8*)&Wlo[((size_t)g * NC + 64 + h) * 8] = rl;
        *(ushort8*)&Whi[((size_t)g * NC + 72 + h) * 8] = lh;
        *(ushort8*)&Wlo[((size_t)g * NC + 72 + h) * 8] = ll;
    }
    __syncthreads();

    // ---- MFMA: [32j x 128f] @ [128f x 80c], split-bf16 (3 cross terms) ----
    const int w = t >> 6, lane = t & 63;
    const int m16 = lane & 15, q = lane >> 4;

    float4v acc[5] = {};
    #pragma unroll
    for (int kt = 0; kt < 4; ++kt) {
        short8 ahi = *(const short8*)&Hhi[(w * 16 + m16) * HPAD + kt * 32 + q * 8];
        short8 alo = *(const short8*)&Hlo[(w * 16 + m16) * HPAD + kt * 32 + q * 8];
        #pragma unroll
        for (int nt = 0; nt < 5; ++nt) {
            short8 bhi = *(const short8*)&Whi[((size_t)(kt * 4 + q) * NC + nt * 16 + m16) * 8];
            short8 blo = *(const short8*)&Wlo[((size_t)(kt * 4 + q) * NC + nt * 16 + m16) * 8];
            acc[nt] = __builtin_amdgcn_mfma_f32_16x16x32_bf16(ahi, bhi, acc[nt], 0, 0, 0);
            acc[nt] = __builtin_amdgcn_mfma_f32_16x16x32_bf16(alo, bhi, acc[nt], 0, 0, 0);
            acc[nt] = __builtin_amdgcn_mfma_f32_16x16x32_bf16(ahi, blo, acc[nt], 0, 0, 0);
        }
    }

    // acc[4] col 64+m16: m16<8 -> e_r[h=m16]; m16>=8 -> e_l[h=m16-8]
    const int jbase = j0 + w * 16 + q * 4;
    float ex[4];
    #pragma unroll
    for (int r = 0; r < 4; ++r) ex[r] = expf(acc[4][r]);
    if (m16 >= 8) {
        #pragma unroll
        for (int r = 0; r < 4; ++r)
            expEl[(m16 - 8) * NN + jbase + r] = ex[r];
    }
    #pragma unroll
    for (int r = 0; r < 4; ++r) {
        const int j = jbase + r;
        const size_t base = ((size_t)((j >> 5) * 4 + ((j >> 3) & 3)) * NC) * 8 + (j & 7);
        #pragma unroll
        for (int nt = 0; nt < 4; ++nt) {
            // col c = nt*16+m16 -> h = 2nt + (m16>>3); expEr[h] lives on lane (q, m16'=h)
            const int srcl = (lane & 48) | (nt * 2 + (m16 >> 3));
            const float er = __shfl(ex[r], srcl);
            Bp[base + (size_t)(nt * 16 + m16) * 8] = __float2bfloat16(er * acc[nt][r]);
        }
        const float v = (m16 < 8) ? ex[r] : (m16 == 8 ? 1.0f : 0.0f);
        Bp[base + (size_t)(64 + m16) * 8] = __float2bfloat16(v);
    }
}

// ---------------------------------------------------------------------------
// Kernel 2 (fused, block-local split-K): block = 512 thr (8 waves), 16 rows.
// Wave w computes the 16x80 tile over K-chunk [w*512, (w+1)*512); partials
// reduced through LDS (no global sync, no Cp), then denom + elu + store.
// A f32 0/1 truncated to bf16 in-register (exact).
// ---------------------------------------------------------------------------
__global__ __launch_bounds__(512) void gat_gemm(const float* __restrict__ A,
                                                const __hip_bfloat16* __restrict__ Bp,
                                                const float* __restrict__ expEl,
                                                float* __restrict__ out)
{
    __shared__ float Ls[8 * 16 * LSTR];   // 43 KB
    const int rb   = blockIdx.x;          // 0..255, 16 rows each
    const int wave = threadIdx.x >> 6;    // 0..7 = K-chunk
    const int lane = threadIdx.x & 63;
    const int m16  = lane & 15;
    const int q    = lane >> 4;
    const int row0 = rb * 16;

    float4v acc[5] = {};

    const int k0 = wave * 512;
    const unsigned int* Au = (const unsigned int*)A;
    const short* Bs = (const short*)Bp;
    const unsigned int* arow = Au + (size_t)(row0 + m16) * NN + q * 8;

    uint4v a0 = *(const uint4v*)(arow + k0);
    uint4v a1 = *(const uint4v*)(arow + k0 + 4);

    #pragma unroll 4
    for (int kt = 0; kt < 16; ++kt) {
        const int kk = k0 + kt * 32;
        short8 afrag;
        afrag[0] = (short)(a0[0] >> 16); afrag[1] = (short)(a0[1] >> 16);
        afrag[2] = (short)(a0[2] >> 16); afrag[3] = (short)(a0[3] >> 16);
        afrag[4] = (short)(a1[0] >> 16); afrag[5] = (short)(a1[1] >> 16);
        afrag[6] = (short)(a1[2] >> 16); afrag[7] = (short)(a1[3] >> 16);

        if (kt + 1 < 16) {                // prefetch next A tile
            a0 = *(const uint4v*)(arow + kk + 32);
            a1 = *(const uint4v*)(arow + kk + 36);
        }

        const int ktg = kk >> 5;
        const short8* bbase = (const short8*)(Bs + ((size_t)(ktg * 4 + q) * NC) * 8);
        #pragma unroll
        for (int nt = 0; nt < 5; ++nt) {
            short8 bfrag = bbase[nt * 16 + m16];
            acc[nt] = __builtin_amdgcn_mfma_f32_16x16x32_bf16(afrag, bfrag, acc[nt], 0, 0, 0);
        }
    }

    // ---- partials -> LDS (stride LSTR=84: q-groups land 16 banks apart) ----
    float* Lw = Ls + wave * (16 * LSTR);
    #pragma unroll
    for (int nt = 0; nt < 5; ++nt) {
        #pragma unroll
        for (int r = 0; r < 4; ++r)       // C/D: col=lane&15, row=(lane>>4)*4+reg
            Lw[(q * 4 + r) * LSTR + nt * 16 + m16] = acc[nt][r];
    }
    __syncthreads();

    // ---- reduce 8 wave-partials + denom + elu + store (1024 outputs) ----
    #pragma unroll
    for (int p = threadIdx.x; p < 1024; p += 512) {
        const int il = p >> 6;            // local row
        const int c  = p & 63;            // h*8+u
        const int h  = c >> 3;
        float T = 0.f, S = 0.f, dg = 0.f;
        #pragma unroll
        for (int w = 0; w < 8; ++w) {
            const float* rowp = Ls + w * (16 * LSTR) + il * LSTR;
            T  += rowp[c];
            S  += rowp[64 + h];
            dg += rowp[72];
        }
        const float el = expEl[h * NN + row0 + il];
        const float denom = ((float)NN - dg) + el * S;
        const float x = el * T / denom;
        out[(size_t)(row0 + il) * 64 + c] = x > 0.f ? x : expf(x) - 1.f;
    }
}

extern "C" void kernel_launch(void* const* d_in, const int* in_sizes, int n_in,
                              void* d_out, int out_size, void* d_ws, size_t ws_size,
                              hipStream_t stream) {
    const float* A  = (const float*)d_in[0];
    const float* H  = (const float*)d_in[1];
    const float* W  = (const float*)d_in[2];
    const float* al = (const float*)d_in[3];
    const float* ar = (const float*)d_in[4];
    float* out = (float*)d_out;

    // workspace layout
    float* expEl = (float*)d_ws;                                   // 8*4096 f32 = 128 KB
    __hip_bfloat16* Bp = (__hip_bfloat16*)((char*)d_ws + 131072);  // 128*4*80*8 bf16 = 640 KB

    gat_prep<<<NN / 32, 128, 0, stream>>>(H, W, al, ar, expEl, Bp);
    gat_gemm<<<NN / 16, 512, 0, stream>>>(A, Bp, expEl, out);
}